// Round 2
// 446.892 us; speedup vs baseline: 1.0492x; 1.0492x over previous
//
#include <hip/hip_runtime.h>
#include <hip/hip_fp16.h>

#define D 64
constexpr int TPB = 256;             // scans + spmm block size
constexpr int PTPB = 512;            // passA/passB block size
constexpr int CTPB = 512;            // passC block size
constexpr int VSHIFT = 9;            // 512 nodes per bucket
constexpr int VNODES = 1 << VSHIFT;  // 512
constexpr int CHUNK = 16384;         // edges per partition block
typedef unsigned short u16;

__device__ inline unsigned h2pack(float a, float b) {
    unsigned lo = __half_as_ushort(__float2half_rn(a));
    unsigned hi = __half_as_ushort(__float2half_rn(b));
    return lo | (hi << 16);
}

// ---------------- passA: per-chunk histogram over buckets --------------------
__global__ void passA_kernel(const int* __restrict__ col, int* __restrict__ H,
                             int E, int NBLK, int NBUK) {
    __shared__ int h[VNODES];
    int t = threadIdx.x, blk = blockIdx.x;
    for (int b = t; b < NBUK; b += PTPB) h[b] = 0;
    __syncthreads();
    int base = blk * CHUNK, end = min(base + CHUNK, E);
    for (int i = base + t; i < end; i += PTPB)
        atomicAdd(&h[col[i] >> VSHIFT], 1);
    __syncthreads();
    for (int b = t; b < NBUK; b += PTPB) H[(size_t)b * NBLK + blk] = h[b];
}

// ---------------- scan stage 1 -----------------------------------------------
__global__ void scan1_kernel(const int* __restrict__ v, int* __restrict__ part,
                             int* __restrict__ bsum, int M) {
    __shared__ int s[TPB];
    int t = threadIdx.x;
    int i = blockIdx.x * TPB + t;
    int x0 = (i < M) ? v[i] : 0;
    s[t] = x0;
    __syncthreads();
    for (int off = 1; off < TPB; off <<= 1) {
        int x = (t >= off) ? s[t - off] : 0;
        __syncthreads();
        s[t] += x;
        __syncthreads();
    }
    if (i < M) part[i] = s[t];
    if (t == TPB - 1) bsum[blockIdx.x] = s[t];
}

// ---------------- scan stage 2 -----------------------------------------------
__global__ void scan2_kernel(const int* __restrict__ bsum, int* __restrict__ boff, int nb) {
    __shared__ int s[1024];
    int t = threadIdx.x;
    int v = (t < nb) ? bsum[t] : 0;
    s[t] = v;
    __syncthreads();
    for (int off = 1; off < 1024; off <<= 1) {
        int x = (t >= off) ? s[t - off] : 0;
        __syncthreads();
        s[t] += x;
        __syncthreads();
    }
    if (t < nb) boff[t] = s[t] - v;   // exclusive
}

// ---------------- scan stage 3 -----------------------------------------------
__global__ void scan3_kernel(const int* __restrict__ v, const int* __restrict__ part,
                             const int* __restrict__ boff, int* __restrict__ pos, int M) {
    int i = blockIdx.x * blockDim.x + threadIdx.x;
    if (i < M) pos[i] = boff[blockIdx.x] + part[i] - v[i];
}

// ---------------- passB: partition edges into bucket-sorted tmp --------------
__global__ void passB_kernel(const int* __restrict__ row, const int* __restrict__ col,
                             const int* __restrict__ pos, unsigned* __restrict__ tmp,
                             int E, int NBLK, int NBUK) {
    __shared__ int cur[VNODES];
    int t = threadIdx.x, blk = blockIdx.x;
    for (int b = t; b < NBUK; b += PTPB) cur[b] = pos[(size_t)b * NBLK + blk];
    __syncthreads();
    int base = blk * CHUNK, end = min(base + CHUNK, E);
    for (int i = base + t; i < end; i += PTPB) {
        int c = col[i];
        int p = atomicAdd(&cur[c >> VSHIFT], 1);
        tmp[p] = ((unsigned)(c & (VNODES - 1)) << 18) | (unsigned)row[i];
    }
}

// ---------------- passC: fused deg + dis + row_ptr + placement + Z0 ----------
// One block (512 thr) per bucket of 512 nodes. After placing srow, also emits
// Z0 = fp16(dis ⊙ emb) for its nodes. Block 0 additionally zeroes row N of
// both fp16 state buffers (zero-row used by spmm's branch-free tail padding).
__global__ void passC_kernel(const unsigned* __restrict__ tmp, const int* __restrict__ pos,
                             int* __restrict__ row_ptr, float* __restrict__ dis,
                             int* __restrict__ srow,
                             const float2* __restrict__ emb2, unsigned* __restrict__ z,
                             unsigned* __restrict__ zb,
                             int N, int E, int NBLK, int NBUK) {
    __shared__ int cnt[VNODES], sc[VNODES], cur[VNODES];
    __shared__ int se[2];
    int b = blockIdx.x, t = threadIdx.x;
    int nodeBase = b << VSHIFT;
    if (t == 0) {
        se[0] = pos[(size_t)b * NBLK];
        se[1] = (b + 1 < NBUK) ? pos[(size_t)(b + 1) * NBLK] : E;
    }
    cnt[t] = 0;
    if (b == 0 && t < 32) {            // zero row N of both state buffers
        z[(size_t)N * 32 + t] = 0;
        zb[(size_t)N * 32 + t] = 0;
    }
    __syncthreads();
    int start = se[0], end = se[1];
    for (int i = start + t; i < end; i += CTPB)
        atomicAdd(&cnt[tmp[i] >> 18], 1);
    __syncthreads();
    sc[t] = cnt[t];
    __syncthreads();
    // Blelloch exclusive scan over 512 counts
    for (int off = 1; off < VNODES; off <<= 1) {
        int i = (t + 1) * (off << 1) - 1;
        if (i < VNODES) sc[i] += sc[i - off];
        __syncthreads();
    }
    if (t == 0) sc[VNODES - 1] = 0;
    __syncthreads();
    for (int off = VNODES / 2; off >= 1; off >>= 1) {
        int i = (t + 1) * (off << 1) - 1;
        if (i < VNODES) { int x = sc[i - off]; sc[i - off] = sc[i]; sc[i] += x; }
        __syncthreads();
    }
    {
        int rp = start + sc[t];
        cur[t] = rp;
        int node = nodeBase + t;
        if (node < N) {
            row_ptr[node] = rp;
            int d = cnt[t];
            dis[node] = (d > 0) ? rsqrtf((float)d) : 0.0f;
        }
    }
    if (b == 0 && t == 0) row_ptr[N] = E;
    __syncthreads();
    for (int i = start + t; i < end; i += CTPB) {
        unsigned pk = tmp[i];
        int p = atomicAdd(&cur[pk >> 18], 1);
        srow[p] = (int)(pk & 0x3FFFFu);
    }
    // Z0 for this bucket's nodes: coalesced float2 reads / dword writes
    for (int i = t; i < (VNODES << 5); i += CTPB) {
        int k = i >> 5;
        int node = nodeBase + k;
        if (node < N) {
            int d = cnt[k];
            float dv = (d > 0) ? rsqrtf((float)d) : 0.0f;
            size_t o = (size_t)node * 32 + (i & 31);
            float2 x = emb2[o];
            z[o] = h2pack(dv * x.x, dv * x.y);
        }
    }
}

// ---------------- CSR SpMM: two nodes per wave, dwordx4 fp16x8 gathers -------
// Half-wave h (32 lanes) handles node 2*wave+h. Within a half, 8 lanes cover
// one 128B src row (16B/lane), so one wave VMEM instruction gathers 8 edge
// rows (4 per half) — 4x fewer VMEM/shfl instructions than the dword scheme.
// Invalid tail lanes are redirected to the all-zero row at index N, keeping
// the inner loop branch-free with 8 dwordx4 loads in flight.
#define ACC8(u) do { \
    a0 += __half2float(__ushort_as_half((u16)((u).x & 0xffff))); \
    a1 += __half2float(__ushort_as_half((u16)((u).x >> 16)));    \
    a2 += __half2float(__ushort_as_half((u16)((u).y & 0xffff))); \
    a3 += __half2float(__ushort_as_half((u16)((u).y >> 16)));    \
    a4 += __half2float(__ushort_as_half((u16)((u).z & 0xffff))); \
    a5 += __half2float(__ushort_as_half((u16)((u).z >> 16)));    \
    a6 += __half2float(__ushort_as_half((u16)((u).w & 0xffff))); \
    a7 += __half2float(__ushort_as_half((u16)((u).w >> 16)));    \
} while (0)

template <int MODE, bool WRITE_DST>
__global__ void spmm_kernel(const int* __restrict__ row_ptr, const int* __restrict__ srow,
                            const float* __restrict__ dis,
                            const unsigned* __restrict__ src, unsigned* __restrict__ dst,
                            float2* __restrict__ out2, const float2* __restrict__ emb2,
                            int N) {
    int wave = (blockIdx.x * blockDim.x + threadIdx.x) >> 6;
    int lane = threadIdx.x & 63;
    int half = lane >> 5;
    int sub  = lane & 31;
    int node = 2 * wave + half;
    if (node >= N) return;
    int start = row_ptr[node];
    int end   = row_ptr[node + 1];
    int hb = half << 5;
    int rg = sub >> 3;                 // row-within-group: 0..3
    int q  = sub & 7;                  // 16B slot within row: 0..7
    const uint4* __restrict__ s4 = (const uint4*)src;
    float a0 = 0, a1 = 0, a2 = 0, a3 = 0, a4 = 0, a5 = 0, a6 = 0, a7 = 0;
    for (int base = start; base < end; base += 32) {
        int mye = base + sub;
        int rr = (mye < end) ? srow[mye] : 0;   // 128B coalesced per half
        int cnt = end - base;                   // valid iff (4k+rg) < cnt
        int r0 = __shfl(rr, hb +  0 + rg);
        int r1 = __shfl(rr, hb +  4 + rg);
        int r2 = __shfl(rr, hb +  8 + rg);
        int r3 = __shfl(rr, hb + 12 + rg);
        int r4 = __shfl(rr, hb + 16 + rg);
        int r5 = __shfl(rr, hb + 20 + rg);
        int r6 = __shfl(rr, hb + 24 + rg);
        int r7 = __shfl(rr, hb + 28 + rg);
        r0 = ( 0 + rg < cnt) ? r0 : N;          // zero-row padding
        r1 = ( 4 + rg < cnt) ? r1 : N;
        r2 = ( 8 + rg < cnt) ? r2 : N;
        r3 = (12 + rg < cnt) ? r3 : N;
        r4 = (16 + rg < cnt) ? r4 : N;
        r5 = (20 + rg < cnt) ? r5 : N;
        r6 = (24 + rg < cnt) ? r6 : N;
        r7 = (28 + rg < cnt) ? r7 : N;
        uint4 u0 = s4[(size_t)r0 * 8 + q];      // 8 independent 16B gathers
        uint4 u1 = s4[(size_t)r1 * 8 + q];
        uint4 u2 = s4[(size_t)r2 * 8 + q];
        uint4 u3 = s4[(size_t)r3 * 8 + q];
        uint4 u4 = s4[(size_t)r4 * 8 + q];
        uint4 u5 = s4[(size_t)r5 * 8 + q];
        uint4 u6 = s4[(size_t)r6 * 8 + q];
        uint4 u7 = s4[(size_t)r7 * 8 + q];
        ACC8(u0); ACC8(u1); ACC8(u2); ACC8(u3);
        ACC8(u4); ACC8(u5); ACC8(u6); ACC8(u7);
    }
    // reduce across the 4 row-groups (lane bits 3 and 4; never crosses halves)
    a0 += __shfl_xor(a0, 8);  a1 += __shfl_xor(a1, 8);
    a2 += __shfl_xor(a2, 8);  a3 += __shfl_xor(a3, 8);
    a4 += __shfl_xor(a4, 8);  a5 += __shfl_xor(a5, 8);
    a6 += __shfl_xor(a6, 8);  a7 += __shfl_xor(a7, 8);
    a0 += __shfl_xor(a0, 16); a1 += __shfl_xor(a1, 16);
    a2 += __shfl_xor(a2, 16); a3 += __shfl_xor(a3, 16);
    a4 += __shfl_xor(a4, 16); a5 += __shfl_xor(a5, 16);
    a6 += __shfl_xor(a6, 16); a7 += __shfl_xor(a7, 16);
    if (rg != 0) return;                       // lanes 0..7 of each half finish
    float dc = dis[node];
    float e0 = dc * a0, e1 = dc * a1, e2 = dc * a2, e3 = dc * a3;
    float e4 = dc * a4, e5 = dc * a5, e6 = dc * a6, e7 = dc * a7;
    if (WRITE_DST) {                           // pre-scaled next state (fp16)
        uint4 pk;
        pk.x = h2pack(dc * e0, dc * e1);
        pk.y = h2pack(dc * e2, dc * e3);
        pk.z = h2pack(dc * e4, dc * e5);
        pk.w = h2pack(dc * e6, dc * e7);
        ((uint4*)dst)[(size_t)node * 8 + q] = pk;
    }
    size_t fo = (size_t)node * 16 + q * 2;     // float4 index, dims 8q..8q+7
    float4* __restrict__ o4 = (float4*)out2;
    float4 c0, c1;
    if (MODE == 0) {
        const float4* __restrict__ e4p = (const float4*)emb2;
        c0 = e4p[fo]; c1 = e4p[fo + 1];
        c0.x += e0; c0.y += e1; c0.z += e2; c0.w += e3;
        c1.x += e4; c1.y += e5; c1.z += e6; c1.w += e7;
    } else if (MODE == 1) {
        c0 = o4[fo]; c1 = o4[fo + 1];
        c0.x += e0; c0.y += e1; c0.z += e2; c0.w += e3;
        c1.x += e4; c1.y += e5; c1.z += e6; c1.w += e7;
    } else {
        c0 = o4[fo]; c1 = o4[fo + 1];
        c0.x = (c0.x + e0) * 0.25f; c0.y = (c0.y + e1) * 0.25f;
        c0.z = (c0.z + e2) * 0.25f; c0.w = (c0.w + e3) * 0.25f;
        c1.x = (c1.x + e4) * 0.25f; c1.y = (c1.y + e5) * 0.25f;
        c1.z = (c1.z + e6) * 0.25f; c1.w = (c1.w + e7) * 0.25f;
    }
    o4[fo] = c0; o4[fo + 1] = c1;
}

extern "C" void kernel_launch(void* const* d_in, const int* in_sizes, int n_in,
                              void* d_out, int out_size, void* d_ws, size_t ws_size,
                              hipStream_t stream) {
    const int* edge = (const int*)d_in[0];
    const float* emb = (const float*)d_in[1];
    const int E = in_sizes[0] / 2;       // 4,000,000
    const int N = in_sizes[1] / D;       // 150,000
    float2* out2 = (float2*)d_out;

    const int* row = edge;
    const int* col = edge + E;

    const int NBLK = (E + CHUNK - 1) / CHUNK;           // 245
    const int NBUK = (N + VNODES - 1) >> VSHIFT;        // 293
    const int M = NBUK * NBLK;                          // 71,785
    const int nbH = (M + TPB - 1) / TPB;                // 281 (<=1024 for scan2)

    // workspace layout (~72.5 MB; no aliasing). A/B carry one extra zero row.
    unsigned* A       = (unsigned*)d_ws;                 // (N+1)*32 dwords (fp16x2 Z ping)
    unsigned* B       = A + (size_t)(N + 1) * 32;        // (N+1)*32 dwords (Z pong)
    int*      srow    = (int*)(B + (size_t)(N + 1) * 32);// E ints
    int*      row_ptr = srow + E;                        // N+1 ints
    float*    dis     = (float*)(row_ptr + N + 1);       // N floats
    int*      H       = (int*)(dis + N);                 // M ints
    int*      part    = H + M;                           // M ints
    int*      pos     = part + M;                        // M ints
    int*      bsum    = pos + M;                         // nbH ints
    int*      boff    = bsum + nbH;                      // nbH ints
    unsigned* tmp     = (unsigned*)(boff + nbH);         // E dwords (16 MB)

    const int spmm_blocks = (((N + 1) / 2) * 64 + TPB - 1) / TPB;   // 2 nodes/wave

    // ---- radix partition by destination bucket + fused CSR/deg/dis/Z0 build
    passA_kernel<<<NBLK, PTPB, 0, stream>>>(col, H, E, NBLK, NBUK);
    scan1_kernel<<<nbH, TPB, 0, stream>>>(H, part, bsum, M);
    scan2_kernel<<<1, 1024, 0, stream>>>(bsum, boff, nbH);
    scan3_kernel<<<nbH, TPB, 0, stream>>>(H, part, boff, pos, M);
    passB_kernel<<<NBLK, PTPB, 0, stream>>>(row, col, pos, tmp, E, NBLK, NBUK);
    passC_kernel<<<NBUK, CTPB, 0, stream>>>(tmp, pos, row_ptr, dis, srow,
                                            (const float2*)emb, A, B, N, E, NBLK, NBUK);

    // ---- layer 1: out = emb + embs ; B = pre-scaled next state (fp16)
    spmm_kernel<0, true><<<spmm_blocks, TPB, 0, stream>>>(row_ptr, srow, dis, A, B,
                                                          out2, (const float2*)emb, N);
    // ---- layer 2: out += embs ; A = next state
    spmm_kernel<1, true><<<spmm_blocks, TPB, 0, stream>>>(row_ptr, srow, dis, B, A,
                                                          out2, (const float2*)emb, N);
    // ---- layer 3: out = (out + embs) * 0.25
    spmm_kernel<2, false><<<spmm_blocks, TPB, 0, stream>>>(row_ptr, srow, dis, A, nullptr,
                                                           out2, (const float2*)emb, N);
}